// Round 2
// baseline (981.681 us; speedup 1.0000x reference)
//
#include <hip/hip_runtime.h>

typedef unsigned short u16;
typedef unsigned int   u32;
typedef short s16x8 __attribute__((ext_vector_type(8)));   // 8 x bf16 bits (4 VGPRs)
typedef float f32x4 __attribute__((ext_vector_type(4)));   // MFMA accumulator

#define NPTS   16384
#define KNNK   20
#define LTOP   24      // per-wave / merged superset size (margin 4 over K)
#define CAP    16
#define CHUNK  4096

#define MFMA_BF16 __builtin_amdgcn_mfma_f32_16x16x32_bf16

__device__ __forceinline__ u16 f2bf(float x) {
  u32 u = __builtin_bit_cast(u32, x);
  u32 r = (u + 0x7FFFu + ((u >> 16) & 1u)) >> 16;   // RNE
  return (u16)r;
}
__device__ __forceinline__ float bf2f(u16 b) {
  u32 u = ((u32)b) << 16;
  return __builtin_bit_cast(float, u);
}

// ---------------------------------------------------------------- prep: pos4 = (x,y,z,|p|^2)
__global__ __launch_bounds__(256) void knnconv_prep(const float* __restrict__ pos,
                                                    float4* __restrict__ pos4) {
  int i = blockIdx.x * 256 + threadIdx.x;
  float x = pos[i * 3 + 0], y = pos[i * 3 + 1], z = pos[i * 3 + 2];
  float sq = (x * x + y * y) + z * z;    // f32 screen only; f64 re-rank decides order
  pos4[i] = make_float4(x, y, z, sq);
}

// ---------------------------------------------------------------- exact 20-NN
// block = 4 waves x 64 lanes; lane = query (64 queries/block), wave = candidate quarter.
// f32 screen keeps per-wave top-24; 4-way merge -> 24-superset; f64 re-rank -> final 20.
#define CHAIN_INSERT(V, VI)                                   \
  { float _v = (V); int _vi = (VI);                           \
    _Pragma("unroll")                                         \
    for (int j = 0; j < LTOP; ++j) {                          \
      bool lt = _v < top[j];                                  \
      float ov = top[j]; int ovi = topi[j];                   \
      top[j]  = lt ? _v  : ov;                                \
      topi[j] = lt ? _vi : ovi;                               \
      _v  = lt ? ov  : _v;                                    \
      _vi = lt ? ovi : _vi;                                   \
    } }

#define FLUSH_STACK()                                         \
  { _Pragma("unroll 1")                                       \
    for (int e = 0; e < CAP; ++e) {                           \
      bool m = e < cnt;                                       \
      float v = m ? sd[e * 256 + tid] : __builtin_inff();     \
      int  vi = m ? si[e * 256 + tid] : 0;                    \
      CHAIN_INSERT(v, vi);                                    \
    }                                                         \
    thr = top[LTOP - 1];                                      \
    cnt = 0; }

__global__ __launch_bounds__(256) void knnconv_knn(const float4* __restrict__ pos4,
                                                   int* __restrict__ knn_out) {
  // one 80KB block, regions aliased across phases:
  //  [0,16K)  sd (stacks, dead after final flush)   } phase3: d64 [0,12K), midx [12K,18K)
  //  [16K,32K) si (dead after final flush)          }
  //  [32K,56K) md  per-wave sorted f32 lists (24)
  //  [56K,80K) mi  per-wave sorted idx lists (24)
  __shared__ char lds[81920];
  float* sd   = (float*)lds;
  int*   si   = (int*)(lds + 16384);
  float* md   = (float*)(lds + 32768);
  int*   mi   = (int*)(lds + 57344);
  double* d64 = (double*)lds;
  int*   midx = (int*)(lds + 12288);

  const int tid  = threadIdx.x;
  const int lane = tid & 63;
  const int wv   = tid >> 6;
  const int q    = blockIdx.x * 64 + lane;
  const float4 qp = pos4[q];

  float top[LTOP]; int topi[LTOP];
  #pragma unroll
  for (int j = 0; j < LTOP; ++j) { top[j] = __builtin_inff(); topi[j] = 0; }
  float thr = __builtin_inff();
  int cnt = 0;
  const int cbase = wv * CHUNK;

  for (int t = 0; t < CHUNK; ++t) {
    float4 cd = pos4[cbase + t];
    float dot = qp.x * cd.x + qp.y * cd.y + qp.z * cd.z;   // fma ok: screen only
    float d2  = (qp.w + cd.w) - 2.0f * dot;
    if (d2 < thr) {
      sd[cnt * 256 + tid] = d2; si[cnt * 256 + tid] = cbase + t; ++cnt;
    }
    if (__ballot(cnt == CAP)) {           // all-lane consolidation
      FLUSH_STACK();
    }
  }
  FLUSH_STACK();                          // final flush; sd/si dead after this

  #pragma unroll
  for (int j = 0; j < LTOP; ++j) {
    md[(wv * 64 + lane) * LTOP + j] = top[j];
    mi[(wv * 64 + lane) * LTOP + j] = topi[j];
  }
  __syncthreads();

  // 4-way merge of sorted f32 partials -> 24-candidate superset per query.
  if (lane < 16) {
    int ql = wv * 16 + lane;
    int h0 = 0, h1 = 0, h2 = 0, h3 = 0;   // named heads (no runtime-indexed reg arrays)
    for (int r = 0; r < LTOP; ++r) {      // heads stay <= 23 while r<24
      float c0 = md[(0 * 64 + ql) * LTOP + h0], c1 = md[(1 * 64 + ql) * LTOP + h1];
      float c2 = md[(2 * 64 + ql) * LTOP + h2], c3 = md[(3 * 64 + ql) * LTOP + h3];
      float bv = c0; int bw = 0;
      if (c1 < bv) { bv = c1; bw = 1; }
      if (c2 < bv) { bv = c2; bw = 2; }
      if (c3 < bv) { bv = c3; bw = 3; }
      int hb = (bw == 0) ? h0 : (bw == 1) ? h1 : (bw == 2) ? h2 : h3;
      midx[ql * LTOP + r] = mi[(bw * 64 + ql) * LTOP + hb];
      h0 += (bw == 0); h1 += (bw == 1); h2 += (bw == 2); h3 += (bw == 3);
    }
  }
  __syncthreads();

  // f64 distance for each of 64 queries x 24 candidates (exact ordering:
  // products of f32 are exact in f64; expanded form matches ref up to ~1e-16).
  for (int s = 0; s < 6; ++s) {
    int task = s * 256 + tid;             // 1536 tasks
    int ql = task / LTOP, j = task - ql * LTOP;
    int idx = midx[ql * LTOP + j];
    float4 P = pos4[blockIdx.x * 64 + ql];
    float4 C = pos4[idx];
    double qx = P.x, qy = P.y, qz = P.z;
    double cx = C.x, cy = C.y, cz = C.z;
    double sqq = qx * qx + qy * qy + qz * qz;
    double sqc = cx * cx + cy * cy + cz * cz;
    double dot = qx * cx + qy * cy + qz * cz;
    d64[ql * LTOP + j] = (sqq + sqc) - 2.0 * dot;
  }
  __syncthreads();

  // rank-count selection: keep the 20 lexicographically-smallest (d64, idx).
  for (int s = 0; s < 6; ++s) {
    int task = s * 256 + tid;
    int ql = task / LTOP, j = task - ql * LTOP;
    double dj = d64[ql * LTOP + j];
    int    ij = midx[ql * LTOP + j];
    int rank = 0;
    #pragma unroll
    for (int k = 0; k < LTOP; ++k) {
      double dk = d64[ql * LTOP + k];
      int    ik = midx[ql * LTOP + k];
      rank += (dk < dj || (dk == dj && ik < ij)) ? 1 : 0;
    }
    if (rank < KNNK)
      knn_out[(blockIdx.x * 64 + ql) * KNNK + rank] = ij;
  }
}

// ---------------------------------------------------------------- precompute a = f@W1d (bf16), c = f@(W1c-W1d)+b1 (f32)
// One fused GEMM: [16384,128] @ [128,256].  64-row tile per block, 4 waves x 4 n-tiles.
__global__ __launch_bounds__(256) void knnconv_prec(const float* __restrict__ feat,
                                                    const float* __restrict__ W1,
                                                    const float* __restrict__ b1,
                                                    u16* __restrict__ a_out,
                                                    float* __restrict__ c_out) {
  __shared__ char sW[65536];   // WT[n=256][k=128] bf16, XOR-swizzled rows (T2 pattern)
  __shared__ char sF[16384];   // FA[m=64][k=128] bf16, XOR-swizzled
  const int tid = threadIdx.x;
  { // stage WT: WT[n][k] = n<128 ? W1d[k][n] : (W1c-W1d)[k][n-128]
    int kk = tid & 127, g = tid >> 7;
    for (int nn = 0; nn < 128; ++nn) {
      int n = g * 128 + nn;
      float v;
      if (g == 0) v = W1[(128 + kk) * 128 + n];
      else { int n2 = n - 128; v = W1[kk * 128 + n2] - W1[(128 + kk) * 128 + n2]; }
      *(u16*)(sW + n * 256 + ((kk * 2) ^ ((n & 7) << 4))) = f2bf(v);
    }
  }
  { // stage FA rows (bf16x8 per lane)
    int sub = tid & 15, r0 = tid >> 4;
    int m0 = blockIdx.x * 64;
    for (int rr = 0; rr < 4; ++rr) {
      int r = r0 + rr * 16;
      const float* src = feat + (m0 + r) * 128 + sub * 8;
      float4 v0 = *(const float4*)src;
      float4 v1 = *(const float4*)(src + 4);
      u32 p0 = (u32)f2bf(v0.x) | ((u32)f2bf(v0.y) << 16);
      u32 p1 = (u32)f2bf(v0.z) | ((u32)f2bf(v0.w) << 16);
      u32 p2 = (u32)f2bf(v1.x) | ((u32)f2bf(v1.y) << 16);
      u32 p3 = (u32)f2bf(v1.z) | ((u32)f2bf(v1.w) << 16);
      *(uint4*)(sF + r * 256 + ((sub * 16) ^ ((r & 7) << 4))) = make_uint4(p0, p1, p2, p3);
    }
  }
  __syncthreads();
  const int lane = tid & 63, wv = tid >> 6;
  const int l15 = lane & 15, l4 = lane >> 4;
  f32x4 acc[4][4];
  #pragma unroll
  for (int a = 0; a < 4; ++a)
    #pragma unroll
    for (int b = 0; b < 4; ++b) acc[a][b] = (f32x4){0.f, 0.f, 0.f, 0.f};
  #pragma unroll
  for (int kk = 0; kk < 4; ++kk) {
    int kb = kk * 64 + l4 * 16;
    s16x8 af[4], bfr[4];
    #pragma unroll
    for (int mt = 0; mt < 4; ++mt) {
      int row = mt * 16 + l15;
      af[mt] = *(const s16x8*)(sF + row * 256 + (kb ^ ((row & 7) << 4)));
    }
    #pragma unroll
    for (int nt = 0; nt < 4; ++nt) {
      int n = (wv * 4 + nt) * 16 + l15;
      bfr[nt] = *(const s16x8*)(sW + n * 256 + (kb ^ ((n & 7) << 4)));
    }
    #pragma unroll
    for (int mt = 0; mt < 4; ++mt)
      #pragma unroll
      for (int nt = 0; nt < 4; ++nt)
        acc[mt][nt] = MFMA_BF16(af[mt], bfr[nt], acc[mt][nt], 0, 0, 0);
  }
  int m0 = blockIdx.x * 64;
  #pragma unroll
  for (int nt = 0; nt < 4; ++nt) {
    int n = (wv * 4 + nt) * 16 + l15;         // tile fully on one side of 128 boundary
    float bias = (n >= 128) ? b1[n - 128] : 0.0f;
    #pragma unroll
    for (int mt = 0; mt < 4; ++mt)
      #pragma unroll
      for (int r = 0; r < 4; ++r) {
        int m = m0 + mt * 16 + l4 * 4 + r;    // C/D: row=(l>>4)*4+reg, col=l&15 (m89)
        float v = acc[mt][nt][r];
        if (n < 128) a_out[m * 128 + n] = f2bf(v);
        else         c_out[m * 128 + (n - 128)] = v + bias;
      }
  }
}

// ---------------------------------------------------------------- fused gather + relu + GEMM2 + max
// block = 8 queries (160 edge rows = 10 m-tiles), 4 waves x 2 n-tiles, K=128.
__global__ __launch_bounds__(256) void knnconv_conv(const int* __restrict__ knn,
                                                    const u16* __restrict__ a_in,
                                                    const float* __restrict__ c_in,
                                                    const float* __restrict__ W2,
                                                    const float* __restrict__ b2,
                                                    float* __restrict__ out) {
  __shared__ char lds[77824];     // [0,40960): A / H2  | [40960,73728): W2T | [73728,77824): c rows
  char* sA = lds;
  char* sW = lds + 40960;
  char* sC = lds + 73728;
  const int tid = threadIdx.x;
  const int q0 = blockIdx.x * 8;

  { // stage c rows for the 8 queries (read once, reused by 20 edge rows each)
    int row = tid >> 5, ch4 = (tid & 31) * 4;
    *(float4*)(sC + (row * 128 + ch4) * 4) = *(const float4*)(c_in + (q0 + row) * 128 + ch4);
  }
  __syncthreads();
  { // stage W2T[n][k] (B needs k-contiguous per n), XOR-swizzled
    int kk = tid & 127, g = tid >> 7;
    for (int nn = 0; nn < 64; ++nn) {
      int n = g * 64 + nn;
      *(u16*)(sW + n * 256 + ((kk * 2) ^ ((n & 7) << 4))) = f2bf(W2[kk * 128 + n]);
    }
  }
  { // stage A: row r = (query il, neighbor ke): relu(a[idx] + c[il]) -> bf16, swizzled
    int sub = tid & 15, rr = tid >> 4;
    for (int p = 0; p < 10; ++p) {
      int r = p * 16 + rr;
      int il = r / 20;
      int ke = r - il * 20;
      int idx = knn[(q0 + il) * KNNK + ke];
      uint4 av = *(const uint4*)(a_in + idx * 128 + sub * 8);
      float4 c0 = *(const float4*)(sC + (il * 128 + sub * 8) * 4);
      float4 c1 = *(const float4*)(sC + (il * 128 + sub * 8 + 4) * 4);
      float h0 = fmaxf(bf2f((u16)(av.x & 0xFFFF)) + c0.x, 0.f);
      float h1 = fmaxf(bf2f((u16)(av.x >> 16))    + c0.y, 0.f);
      float h2 = fmaxf(bf2f((u16)(av.y & 0xFFFF)) + c0.z, 0.f);
      float h3 = fmaxf(bf2f((u16)(av.y >> 16))    + c0.w, 0.f);
      float h4 = fmaxf(bf2f((u16)(av.z & 0xFFFF)) + c1.x, 0.f);
      float h5 = fmaxf(bf2f((u16)(av.z >> 16))    + c1.y, 0.f);
      float h6 = fmaxf(bf2f((u16)(av.w & 0xFFFF)) + c1.z, 0.f);
      float h7 = fmaxf(bf2f((u16)(av.w >> 16))    + c1.w, 0.f);
      u32 p0 = (u32)f2bf(h0) | ((u32)f2bf(h1) << 16);
      u32 p1 = (u32)f2bf(h2) | ((u32)f2bf(h3) << 16);
      u32 p2 = (u32)f2bf(h4) | ((u32)f2bf(h5) << 16);
      u32 p3 = (u32)f2bf(h6) | ((u32)f2bf(h7) << 16);
      *(uint4*)(sA + r * 256 + ((sub * 16) ^ ((r & 7) << 4))) = make_uint4(p0, p1, p2, p3);
    }
  }
  __syncthreads();
  const int lane = tid & 63, wv = tid >> 6;
  const int l15 = lane & 15, l4 = lane >> 4;
  f32x4 acc[10][2];
  #pragma unroll
  for (int mt = 0; mt < 10; ++mt) { acc[mt][0] = (f32x4){0,0,0,0}; acc[mt][1] = (f32x4){0,0,0,0}; }
  #pragma unroll
  for (int kk = 0; kk < 4; ++kk) {
    int kb = kk * 64 + l4 * 16;
    s16x8 b0, b1r;
    { int n = (wv * 2 + 0) * 16 + l15; b0  = *(const s16x8*)(sW + n * 256 + (kb ^ ((n & 7) << 4))); }
    { int n = (wv * 2 + 1) * 16 + l15; b1r = *(const s16x8*)(sW + n * 256 + (kb ^ ((n & 7) << 4))); }
    #pragma unroll
    for (int mt = 0; mt < 10; ++mt) {
      int row = mt * 16 + l15;
      s16x8 a = *(const s16x8*)(sA + row * 256 + (kb ^ ((row & 7) << 4)));
      acc[mt][0] = MFMA_BF16(a, b0,  acc[mt][0], 0, 0, 0);
      acc[mt][1] = MFMA_BF16(a, b1r, acc[mt][1], 0, 0, 0);
    }
  }
  __syncthreads();              // all waves done reading A before H2 overwrite
  #pragma unroll
  for (int mt = 0; mt < 10; ++mt)
    #pragma unroll
    for (int nt = 0; nt < 2; ++nt) {
      int n = (wv * 2 + nt) * 16 + l15;
      #pragma unroll
      for (int r = 0; r < 4; ++r) {
        int row = mt * 16 + l4 * 4 + r;
        *(u16*)(sA + row * 256 + n * 2) = f2bf(acc[mt][nt][r]);  // H2, plain layout
      }
    }
  __syncthreads();
  { // max over 20 neighbors + b2
    int ch = tid & 127, g = tid >> 7;
    float bias = b2[ch];
    for (int pp = 0; pp < 4; ++pp) {
      int qq = pp * 2 + g;
      float mx = -__builtin_inff();
      #pragma unroll
      for (int e = 0; e < KNNK; ++e)
        mx = fmaxf(mx, bf2f(*(const u16*)(sA + (qq * 20 + e) * 256 + ch * 2)));
      out[(q0 + qq) * 128 + ch] = mx + bias;
    }
  }
}

// ---------------------------------------------------------------- launch
extern "C" void kernel_launch(void* const* d_in, const int* in_sizes, int n_in,
                              void* d_out, int out_size, void* d_ws, size_t ws_size,
                              hipStream_t stream) {
  const float* pos  = (const float*)d_in[0];
  const float* feat = (const float*)d_in[1];
  const float* W1   = (const float*)d_in[2];
  const float* b1   = (const float*)d_in[3];
  const float* W2   = (const float*)d_in[4];
  const float* b2   = (const float*)d_in[5];
  float* out = (float*)d_out;
  char* ws = (char*)d_ws;
  // ws layout: pos4 256KB | knn_idx 1.25MB | a(bf16) 4MB | c(f32) 8MB  = 13.5MB
  float4* pos4 = (float4*)ws;
  int*   knn   = (int*)(ws + 262144);
  u16*   a_buf = (u16*)(ws + 1572864);
  float* c_buf = (float*)(ws + 5767168);
  if (ws_size < 14155776) return;   // insufficient scratch (would corrupt)

  knnconv_prep<<<64, 256, 0, stream>>>(pos, pos4);
  knnconv_knn<<<256, 256, 0, stream>>>(pos4, knn);
  knnconv_prec<<<256, 256, 0, stream>>>(feat, W1, b1, a_buf, c_buf);
  knnconv_conv<<<2048, 256, 0, stream>>>(knn, a_buf, c_buf, W2, b2, out);
}

// Round 4
// 442.538 us; speedup vs baseline: 2.2183x; 2.2183x over previous
//
#include <hip/hip_runtime.h>

typedef unsigned short u16;
typedef unsigned int   u32;
typedef unsigned long long u64;
typedef short s16x8 __attribute__((ext_vector_type(8)));   // 8 x bf16 bits (4 VGPRs)
typedef float f32x4 __attribute__((ext_vector_type(4)));   // MFMA accumulator

#define NPTS   16384
#define KNNK   20
#define L24    24      // per-chunk top-list length (superset margin 4 over K)
#define SLOTS  24      // stack slots per lane
#define TRIG   16      // flush trigger (growth <= 8 per check => cnt <= 23 < SLOTS)
#define NCHUNK 8
#define CHUNK  2048    // candidates per wave in stage-1

#define MFMA_BF16 __builtin_amdgcn_mfma_f32_16x16x32_bf16

__device__ __forceinline__ u16 f2bf(float x) {
  u32 u = __builtin_bit_cast(u32, x);
  u32 r = (u + 0x7FFFu + ((u >> 16) & 1u)) >> 16;   // RNE
  return (u16)r;
}
__device__ __forceinline__ float bf2f(u16 b) {
  u32 u = ((u32)b) << 16;
  return __builtin_bit_cast(float, u);
}

// ---------------------------------------------------------------- prep: pos4 = (x,y,z,|p|^2)
__global__ __launch_bounds__(256) void knnconv_prep(const float* __restrict__ pos,
                                                    float4* __restrict__ pos4) {
  int i = blockIdx.x * 256 + threadIdx.x;
  float x = pos[i * 3 + 0], y = pos[i * 3 + 1], z = pos[i * 3 + 2];
  float sq = (x * x + y * y) + z * z;    // f32 screen only; f64 re-rank decides final set
  pos4[i] = make_float4(x, y, z, sq);
}

// ---------------------------------------------------------------- stage-1 screen
// grid 512 = 256 query-groups x 2 halves; block = 4 waves; lane = query.
// wave chunk = 2048 candidates. Packed u32 key: [d2 bits & ~0x7FF] | local_idx(11b).
// Branchless lazy-stack push; chain-insert (3 instr/stage) only at flushes.
__global__ __launch_bounds__(256) void knnconv_s1(const float4* __restrict__ pos4,
                                                  u16* __restrict__ g1) {
  __shared__ u32 sd[SLOTS * 256];        // 24KB per-lane stacks (bank = tid%32, conflict-free)
  const int tid  = threadIdx.x;
  const int lane = tid & 63;
  const int wv   = tid >> 6;
  const int qg   = blockIdx.x >> 1;
  const int half = blockIdx.x & 1;
  const int q     = qg * 64 + lane;
  const int chunk = half * 4 + wv;       // 0..7
  const int cbase = chunk * CHUNK;
  const float4 qp = pos4[q];

  u32 top[L24];
  #pragma unroll
  for (int j = 0; j < L24; ++j) top[j] = 0xFFFFFFFFu;
  u32 thr = 0xFFFFFFFFu;
  int cnt = 0;
  const float4* cp = pos4 + cbase;

#define FLUSH1()                                                      \
  { _Pragma("unroll 1")                                               \
    for (int e = 0; e < SLOTS; ++e) {                                 \
      if (!__any(e < cnt)) break;                                     \
      u32 v = (e < cnt) ? sd[e * 256 + tid] : 0xFFFFFFFFu;            \
      _Pragma("unroll")                                               \
      for (int j = 0; j < L24; ++j) {                                 \
        bool lt = v < top[j];                                         \
        u32 ov = top[j];                                              \
        top[j] = lt ? v : ov;                                         \
        v      = lt ? ov : v;                                         \
      }                                                               \
    }                                                                 \
    thr = top[L24 - 1];                                               \
    cnt = 0; }

  for (int t0 = 0; t0 < CHUNK; t0 += 8) {
    float4 g[8];
    #pragma unroll
    for (int u = 0; u < 8; ++u) g[u] = cp[t0 + u];     // 8 loads in flight
    #pragma unroll
    for (int u = 0; u < 8; ++u) {
      float dot = qp.x * g[u].x + qp.y * g[u].y + qp.z * g[u].z;
      float d2  = (qp.w + g[u].w) - 2.0f * dot;
      d2 = fmaxf(d2, 0.0f);                            // bit-monotone for >=0
      u32 pk = (__builtin_bit_cast(u32, d2) & 0xFFFFF800u) | (u32)(t0 + u);
      sd[cnt * 256 + tid] = pk;                        // unconditional (slot <= 23 valid)
      cnt += (pk < thr) ? 1 : 0;                       // branchless accept
    }
    if (__any(cnt >= TRIG)) { FLUSH1(); }
  }
  FLUSH1();                                            // final

  u16* dst = g1 + (q * NCHUNK + chunk) * L24;
  #pragma unroll
  for (int j = 0; j < L24; ++j) dst[j] = (u16)(top[j] & 0x7FFu);   // local idx
}

// ---------------------------------------------------------------- stage-2 exact re-rank
// block = 64 queries, 192-candidate superset each. f64 exact distance -> f32 round
// -> u64 key (dbits<<14 | global idx) in LDS -> rank-count -> top-20 set.
__global__ __launch_bounds__(256) void knnconv_s2(const float4* __restrict__ pos4,
                                                  const u16* __restrict__ g1,
                                                  int* __restrict__ knn_out) {
  __shared__ u64 keys[64 * 192];         // 96KB
  const int tid = threadIdx.x;
  const int q0 = blockIdx.x * 64;

  #pragma unroll 4
  for (int s = 0; s < 48; ++s) {
    int task = s * 256 + tid;            // 12288 tasks
    int ql = task / 192, j = task - ql * 192;
    int chunk = j / L24;
    int cidx = chunk * CHUNK + (int)g1[(q0 + ql) * 192 + j];
    float4 P = pos4[q0 + ql];
    float4 C = pos4[cidx];
    double qx = P.x, qy = P.y, qz = P.z;
    double cx = C.x, cy = C.y, cz = C.z;
    double sqq = qx * qx + qy * qy + qz * qz;
    double sqc = cx * cx + cy * cy + cz * cz;
    double dot = qx * cx + qy * cy + qz * cz;
    double d   = (sqq + sqc) - 2.0 * dot;              // exact to ~1e-16
    float df = fmaxf((float)d, 0.0f);                  // one rounding, 6e-8 rel
    keys[task] = ((u64)__builtin_bit_cast(u32, df) << 14) | (u32)cidx;
  }
  __syncthreads();

  #pragma unroll 2
  for (int s = 0; s < 48; ++s) {
    int task = s * 256 + tid;
    int ql = task / 192;
    u64 kj = keys[task];
    const u64* row = keys + ql * 192;
    int r = 0;
    #pragma unroll 8
    for (int k = 0; k < 192; ++k) r += (row[k] < kj) ? 1 : 0;
    if (r < KNNK)
      knn_out[(q0 + ql) * KNNK + r] = (int)(kj & 0x3FFFu);
  }
}

// ---------------------------------------------------------------- W2 -> pre-swizzled bf16 (one-shot)
__global__ __launch_bounds__(256) void knnconv_w2prep(const float* __restrict__ W2,
                                                      u16* __restrict__ w2bf) {
  int e = blockIdx.x * 256 + threadIdx.x;    // 16384 elements, grid 64
  int n = e >> 7, kk = e & 127;
  w2bf[(n * 256 + ((kk * 2) ^ ((n & 7) << 4))) >> 1] = f2bf(W2[kk * 128 + n]);
}

// ---------------------------------------------------------------- precompute a = f@W1d (bf16), c = f@(W1c-W1d)+b1 (f32)
__global__ __launch_bounds__(256) void knnconv_prec(const float* __restrict__ feat,
                                                    const float* __restrict__ W1,
                                                    const float* __restrict__ b1,
                                                    u16* __restrict__ a_out,
                                                    float* __restrict__ c_out) {
  __shared__ char sW[65536];   // WT[n=256][k=128] bf16, XOR-swizzled rows
  __shared__ char sF[16384];   // FA[m=64][k=128] bf16, XOR-swizzled
  const int tid = threadIdx.x;
  { // stage WT: WT[n][k] = n<128 ? W1d[k][n] : (W1c-W1d)[k][n-128]
    int kk = tid & 127, g = tid >> 7;
    for (int nn = 0; nn < 128; ++nn) {
      int n = g * 128 + nn;
      float v;
      if (g == 0) v = W1[(128 + kk) * 128 + n];
      else { int n2 = n - 128; v = W1[kk * 128 + n2] - W1[(128 + kk) * 128 + n2]; }
      *(u16*)(sW + n * 256 + ((kk * 2) ^ ((n & 7) << 4))) = f2bf(v);
    }
  }
  { // stage FA rows (bf16x8 per lane)
    int sub = tid & 15, r0 = tid >> 4;
    int m0 = blockIdx.x * 64;
    for (int rr = 0; rr < 4; ++rr) {
      int r = r0 + rr * 16;
      const float* src = feat + (m0 + r) * 128 + sub * 8;
      float4 v0 = *(const float4*)src;
      float4 v1 = *(const float4*)(src + 4);
      u32 p0 = (u32)f2bf(v0.x) | ((u32)f2bf(v0.y) << 16);
      u32 p1 = (u32)f2bf(v0.z) | ((u32)f2bf(v0.w) << 16);
      u32 p2 = (u32)f2bf(v1.x) | ((u32)f2bf(v1.y) << 16);
      u32 p3 = (u32)f2bf(v1.z) | ((u32)f2bf(v1.w) << 16);
      *(uint4*)(sF + r * 256 + ((sub * 16) ^ ((r & 7) << 4))) = make_uint4(p0, p1, p2, p3);
    }
  }
  __syncthreads();
  const int lane = tid & 63, wv = tid >> 6;
  const int l15 = lane & 15, l4 = lane >> 4;
  f32x4 acc[4][4];
  #pragma unroll
  for (int a = 0; a < 4; ++a)
    #pragma unroll
    for (int b = 0; b < 4; ++b) acc[a][b] = (f32x4){0.f, 0.f, 0.f, 0.f};
  #pragma unroll
  for (int kk = 0; kk < 4; ++kk) {
    int kb = kk * 64 + l4 * 16;
    s16x8 af[4], bfr[4];
    #pragma unroll
    for (int mt = 0; mt < 4; ++mt) {
      int row = mt * 16 + l15;
      af[mt] = *(const s16x8*)(sF + row * 256 + (kb ^ ((row & 7) << 4)));
    }
    #pragma unroll
    for (int nt = 0; nt < 4; ++nt) {
      int n = (wv * 4 + nt) * 16 + l15;
      bfr[nt] = *(const s16x8*)(sW + n * 256 + (kb ^ ((n & 7) << 4)));
    }
    #pragma unroll
    for (int mt = 0; mt < 4; ++mt)
      #pragma unroll
      for (int nt = 0; nt < 4; ++nt)
        acc[mt][nt] = MFMA_BF16(af[mt], bfr[nt], acc[mt][nt], 0, 0, 0);
  }
  int m0 = blockIdx.x * 64;
  #pragma unroll
  for (int nt = 0; nt < 4; ++nt) {
    int n = (wv * 4 + nt) * 16 + l15;
    float bias = (n >= 128) ? b1[n - 128] : 0.0f;
    #pragma unroll
    for (int mt = 0; mt < 4; ++mt)
      #pragma unroll
      for (int r = 0; r < 4; ++r) {
        int m = m0 + mt * 16 + l4 * 4 + r;    // C/D: row=(l>>4)*4+reg, col=l&15
        float v = acc[mt][nt][r];
        if (n < 128) a_out[m * 128 + n] = f2bf(v);
        else         c_out[m * 128 + (n - 128)] = v + bias;
      }
  }
}

// ---------------------------------------------------------------- fused gather + relu + GEMM2 + max
__global__ __launch_bounds__(256) void knnconv_conv(const int* __restrict__ knn,
                                                    const u16* __restrict__ a_in,
                                                    const float* __restrict__ c_in,
                                                    const u16* __restrict__ w2bf,
                                                    const float* __restrict__ b2,
                                                    float* __restrict__ out) {
  __shared__ char lds[77824];     // [0,40960): A / H2  | [40960,73728): W2T | [73728,77824): c rows
  char* sA = lds;
  char* sW = lds + 40960;
  char* sC = lds + 73728;
  const int tid = threadIdx.x;
  const int q0 = blockIdx.x * 8;

  { // stage c rows for the 8 queries
    int row = tid >> 5, ch4 = (tid & 31) * 4;
    *(float4*)(sC + (row * 128 + ch4) * 4) = *(const float4*)(c_in + (q0 + row) * 128 + ch4);
  }
  __syncthreads();
  { // copy pre-swizzled W2 bf16 (linear copy; layout already swizzled)
    const uint4* src = (const uint4*)w2bf;
    uint4* dst = (uint4*)sW;
    #pragma unroll
    for (int r = 0; r < 8; ++r) dst[r * 256 + tid] = src[r * 256 + tid];
  }
  { // stage A: row r = (query il, neighbor ke): relu(a[idx] + c[il]) -> bf16, swizzled
    int sub = tid & 15, rr = tid >> 4;
    for (int p = 0; p < 10; ++p) {
      int r = p * 16 + rr;
      int il = r / 20;
      int ke = r - il * 20;
      int idx = knn[(q0 + il) * KNNK + ke];
      uint4 av = *(const uint4*)(a_in + idx * 128 + sub * 8);
      float4 c0 = *(const float4*)(sC + (il * 128 + sub * 8) * 4);
      float4 c1 = *(const float4*)(sC + (il * 128 + sub * 8 + 4) * 4);
      float h0 = fmaxf(bf2f((u16)(av.x & 0xFFFF)) + c0.x, 0.f);
      float h1 = fmaxf(bf2f((u16)(av.x >> 16))    + c0.y, 0.f);
      float h2 = fmaxf(bf2f((u16)(av.y & 0xFFFF)) + c0.z, 0.f);
      float h3 = fmaxf(bf2f((u16)(av.y >> 16))    + c0.w, 0.f);
      float h4 = fmaxf(bf2f((u16)(av.z & 0xFFFF)) + c1.x, 0.f);
      float h5 = fmaxf(bf2f((u16)(av.z >> 16))    + c1.y, 0.f);
      float h6 = fmaxf(bf2f((u16)(av.w & 0xFFFF)) + c1.z, 0.f);
      float h7 = fmaxf(bf2f((u16)(av.w >> 16))    + c1.w, 0.f);
      u32 p0 = (u32)f2bf(h0) | ((u32)f2bf(h1) << 16);
      u32 p1 = (u32)f2bf(h2) | ((u32)f2bf(h3) << 16);
      u32 p2 = (u32)f2bf(h4) | ((u32)f2bf(h5) << 16);
      u32 p3 = (u32)f2bf(h6) | ((u32)f2bf(h7) << 16);
      *(uint4*)(sA + r * 256 + ((sub * 16) ^ ((r & 7) << 4))) = make_uint4(p0, p1, p2, p3);
    }
  }
  __syncthreads();
  const int lane = tid & 63, wv = tid >> 6;
  const int l15 = lane & 15, l4 = lane >> 4;
  f32x4 acc[10][2];
  #pragma unroll
  for (int mt = 0; mt < 10; ++mt) { acc[mt][0] = (f32x4){0,0,0,0}; acc[mt][1] = (f32x4){0,0,0,0}; }
  #pragma unroll
  for (int kk = 0; kk < 4; ++kk) {
    int kb = kk * 64 + l4 * 16;
    s16x8 b0, b1r;
    { int n = (wv * 2 + 0) * 16 + l15; b0  = *(const s16x8*)(sW + n * 256 + (kb ^ ((n & 7) << 4))); }
    { int n = (wv * 2 + 1) * 16 + l15; b1r = *(const s16x8*)(sW + n * 256 + (kb ^ ((n & 7) << 4))); }
    #pragma unroll
    for (int mt = 0; mt < 10; ++mt) {
      int row = mt * 16 + l15;
      s16x8 a = *(const s16x8*)(sA + row * 256 + (kb ^ ((row & 7) << 4)));
      acc[mt][0] = MFMA_BF16(a, b0,  acc[mt][0], 0, 0, 0);
      acc[mt][1] = MFMA_BF16(a, b1r, acc[mt][1], 0, 0, 0);
    }
  }
  __syncthreads();              // all waves done reading A before H2 overwrite
  #pragma unroll
  for (int mt = 0; mt < 10; ++mt)
    #pragma unroll
    for (int nt = 0; nt < 2; ++nt) {
      int n = (wv * 2 + nt) * 16 + l15;
      #pragma unroll
      for (int r = 0; r < 4; ++r) {
        int row = mt * 16 + l4 * 4 + r;
        *(u16*)(sA + row * 256 + n * 2) = f2bf(acc[mt][nt][r]);  // H2, plain layout
      }
    }
  __syncthreads();
  { // max over 20 neighbors + b2
    int ch = tid & 127, g = tid >> 7;
    float bias = b2[ch];
    for (int pp = 0; pp < 4; ++pp) {
      int qq = pp * 2 + g;
      float mx = -__builtin_inff();
      #pragma unroll
      for (int e = 0; e < KNNK; ++e)
        mx = fmaxf(mx, bf2f(*(const u16*)(sA + (qq * 20 + e) * 256 + ch * 2)));
      out[(q0 + qq) * 128 + ch] = mx + bias;
    }
  }
}

// ---------------------------------------------------------------- launch
extern "C" void kernel_launch(void* const* d_in, const int* in_sizes, int n_in,
                              void* d_out, int out_size, void* d_ws, size_t ws_size,
                              hipStream_t stream) {
  const float* pos  = (const float*)d_in[0];
  const float* feat = (const float*)d_in[1];
  const float* W1   = (const float*)d_in[2];
  const float* b1   = (const float*)d_in[3];
  const float* W2   = (const float*)d_in[4];
  const float* b2   = (const float*)d_in[5];
  float* out = (float*)d_out;
  char* ws = (char*)d_ws;
  // ws layout:
  //  [0,256K)            pos4 (prep..s2)  -> w2bf (32KB, w2prep..conv)
  //  [256K,1.5M)         knn_idx (s2..conv)
  //  [1.5M,14.1M)        g1 6.3MB (s1..s2)  -> a_buf 4MB + c_buf 8MB (prec..conv)
  float4* pos4  = (float4*)ws;
  u16*    w2bf  = (u16*)ws;
  int*    knn   = (int*)(ws + 262144);
  u16*    g1    = (u16*)(ws + 1572864);
  u16*    a_buf = (u16*)(ws + 1572864);
  float*  c_buf = (float*)(ws + 5767168);
  if (ws_size < 14155776) return;   // insufficient scratch (would corrupt)

  knnconv_prep<<<64, 256, 0, stream>>>(pos, pos4);
  knnconv_s1<<<512, 256, 0, stream>>>(pos4, g1);
  knnconv_s2<<<256, 256, 0, stream>>>(pos4, g1, knn);
  knnconv_w2prep<<<64, 256, 0, stream>>>(W2, w2bf);        // overwrites pos4 (dead)
  knnconv_prec<<<256, 256, 0, stream>>>(feat, W1, b1, a_buf, c_buf);  // overwrites g1 (dead)
  knnconv_conv<<<2048, 256, 0, stream>>>(knn, a_buf, c_buf, w2bf, b2, out);
}

// Round 5
// 389.826 us; speedup vs baseline: 2.5183x; 1.1352x over previous
//
#include <hip/hip_runtime.h>

typedef unsigned short u16;
typedef unsigned int   u32;
typedef unsigned long long u64;
typedef short s16x8 __attribute__((ext_vector_type(8)));   // 8 x bf16 bits (4 VGPRs)
typedef float f32x4 __attribute__((ext_vector_type(4)));   // MFMA accumulator

#define NPTS   16384
#define KNNK   20
#define L24    24      // per-chunk top-list length (superset margin 4 over K)
#define SLOTS  24      // stack slots per lane
#define TRIG   16      // flush trigger (growth <= 8 per check => cnt <= 23 < SLOTS)
#define NCHUNK 8
#define CHUNK  2048    // candidates per chunk (split 4 ways across waves)
#define WCAND  512     // candidates per wave

#define MFMA_BF16 __builtin_amdgcn_mfma_f32_16x16x32_bf16

__device__ __forceinline__ u16 f2bf(float x) {
  u32 u = __builtin_bit_cast(u32, x);
  u32 r = (u + 0x7FFFu + ((u >> 16) & 1u)) >> 16;   // RNE
  return (u16)r;
}
__device__ __forceinline__ float bf2f(u16 b) {
  u32 u = ((u32)b) << 16;
  return __builtin_bit_cast(float, u);
}

// ---------------------------------------------------------------- prep: pos4 = (x,y,z,|p|^2)
__global__ __launch_bounds__(256) void knnconv_prep(const float* __restrict__ pos,
                                                    float4* __restrict__ pos4) {
  int i = blockIdx.x * 256 + threadIdx.x;
  float x = pos[i * 3 + 0], y = pos[i * 3 + 1], z = pos[i * 3 + 2];
  float sq = (x * x + y * y) + z * z;    // f32 screen only; f64 re-rank decides final set
  pos4[i] = make_float4(x, y, z, sq);
}

// ---------------------------------------------------------------- stage-1 screen
// grid 2048 = 256 query-groups x 8 chunks; block = 4 waves; lane = query.
// Each wave scans 512 candidates keeping a sorted packed top-24; pair-carry
// min/max merge at flushes (2 instr/elem, no vcc); 4-way in-block merge emits
// the chunk top-24 (u16 local idx) to global.
__global__ __launch_bounds__(256) void knnconv_s1(const float4* __restrict__ pos4,
                                                  u16* __restrict__ g1) {
  __shared__ u32 lds24[SLOTS * 256];     // 24KB: stacks; aliased as md[4][64][24] after barrier
  u32* sd = lds24;
  u32* md = lds24;
  const int tid  = threadIdx.x;
  const int lane = tid & 63;
  const int wv   = tid >> 6;
  const int qg    = blockIdx.x >> 3;
  const int chunk = blockIdx.x & 7;
  const int q     = qg * 64 + lane;
  const float4 qp = pos4[q];

  u32 top[L24];
  #pragma unroll
  for (int j = 0; j < L24; ++j) top[j] = 0xFFFFFFFFu;
  u32 thr = 0xFFFFFFFFu;
  int cnt = 0;
  const int lbase = wv * WCAND;          // local idx base within chunk (11 bits total)
  const float4* cp = pos4 + chunk * CHUNK + lbase;

#define FLUSH1()                                                      \
  { _Pragma("unroll 1")                                               \
    for (int e = 0; e < SLOTS; e += 2) {                              \
      if (!__any(e < cnt)) break;                                     \
      u32 lo = (e     < cnt) ? sd[e * 256 + tid]       : 0xFFFFFFFFu; \
      u32 hi = (e + 1 < cnt) ? sd[(e + 1) * 256 + tid] : 0xFFFFFFFFu; \
      u32 t0_ = min(lo, hi), t1_ = max(lo, hi);                       \
      lo = t0_; hi = t1_;                                             \
      _Pragma("unroll")                                               \
      for (int j = 0; j < L24; ++j) {                                 \
        u32 t = top[j];                                               \
        u32 m = min(lo, t);                                           \
        u32 x = max(lo, t);                                           \
        top[j] = m;                                                   \
        lo = min(x, hi);                                              \
        hi = max(x, hi);                                              \
      }                                                               \
    }                                                                 \
    thr = top[L24 - 1];                                               \
    cnt = 0; }

  for (int t0 = 0; t0 < WCAND; t0 += 8) {
    float4 g[8];
    #pragma unroll
    for (int u = 0; u < 8; ++u) g[u] = cp[t0 + u];     // wave-uniform (scalar) loads
    #pragma unroll
    for (int u = 0; u < 8; ++u) {
      float dot = qp.x * g[u].x + qp.y * g[u].y + qp.z * g[u].z;
      float d2  = (qp.w + g[u].w) - 2.0f * dot;
      d2 = fmaxf(d2, 0.0f);                            // bit-monotone for >=0 (keeps self-pair)
      u32 pk = (__builtin_bit_cast(u32, d2) & 0xFFFFF800u) | (u32)(lbase + t0 + u);
      sd[cnt * 256 + tid] = pk;                        // unconditional (slot <= 22 valid)
      cnt += (pk < thr) ? 1 : 0;                       // branchless accept
    }
    if (__any(cnt >= TRIG)) { FLUSH1(); }
  }
  FLUSH1();                                            // final

  __syncthreads();                       // all waves done with stacks before md alias
  #pragma unroll
  for (int j = 0; j < L24; ++j) md[(wv * 64 + lane) * L24 + j] = top[j];
  __syncthreads();

  // 4-way merge of sorted packed lists -> chunk top-24; lanes 0..15 per wave.
  if (lane < 16) {
    int ql = wv * 16 + lane;
    int gq = qg * 64 + ql;
    u16* dst = g1 + (gq * NCHUNK + chunk) * L24;
    int h0 = 0, h1 = 0, h2 = 0, h3 = 0;
    for (int r = 0; r < L24; ++r) {       // heads stay <= 23 while r < 24
      u32 c0 = md[(0 * 64 + ql) * L24 + h0], c1 = md[(1 * 64 + ql) * L24 + h1];
      u32 c2 = md[(2 * 64 + ql) * L24 + h2], c3 = md[(3 * 64 + ql) * L24 + h3];
      u32 bv = c0; int bw = 0;
      if (c1 < bv) { bv = c1; bw = 1; }
      if (c2 < bv) { bv = c2; bw = 2; }
      if (c3 < bv) { bv = c3; bw = 3; }
      dst[r] = (u16)(bv & 0x7FFu);       // local idx within chunk
      h0 += (bw == 0); h1 += (bw == 1); h2 += (bw == 2); h3 += (bw == 3);
    }
  }
}

// ---------------------------------------------------------------- stage-2 exact re-rank
// block = 32 queries (48KB keys -> 3 blocks/CU), 192-candidate superset each.
// f64 exact distance -> f32 round -> u64 key (dbits<<14 | idx) -> rank-count.
__global__ __launch_bounds__(256) void knnconv_s2(const float4* __restrict__ pos4,
                                                  const u16* __restrict__ g1,
                                                  int* __restrict__ knn_out) {
  __shared__ u64 keys[32 * 192];         // 48KB
  const int tid = threadIdx.x;
  const int q0 = blockIdx.x * 32;

  #pragma unroll 4
  for (int s = 0; s < 24; ++s) {
    int task = s * 256 + tid;            // 6144 tasks
    int ql = task / 192, j = task - ql * 192;
    int chunk = j / L24;
    int cidx = chunk * CHUNK + (int)g1[(q0 + ql) * 192 + j];
    float4 P = pos4[q0 + ql];
    float4 C = pos4[cidx];
    double qx = P.x, qy = P.y, qz = P.z;
    double cx = C.x, cy = C.y, cz = C.z;
    double sqq = qx * qx + qy * qy + qz * qz;
    double sqc = cx * cx + cy * cy + cz * cz;
    double dot = qx * cx + qy * cy + qz * cz;
    double d   = (sqq + sqc) - 2.0 * dot;              // exact to ~1e-16
    float df = fmaxf((float)d, 0.0f);                  // one rounding, 6e-8 rel
    keys[task] = ((u64)__builtin_bit_cast(u32, df) << 14) | (u32)cidx;
  }
  __syncthreads();

  #pragma unroll 2
  for (int s = 0; s < 24; ++s) {
    int task = s * 256 + tid;
    int ql = task / 192;
    u64 kj = keys[task];
    const u64* row = keys + ql * 192;
    int r = 0;
    #pragma unroll 8
    for (int k = 0; k < 192; ++k) r += (row[k] < kj) ? 1 : 0;
    if (r < KNNK)
      knn_out[(q0 + ql) * KNNK + r] = (int)(kj & 0x3FFFu);
  }
}

// ---------------------------------------------------------------- W1/W2 -> pre-swizzled bf16 (one-shot)
// blocks 0..127: W1 combined [n=256][k=128]; blocks 128..191: W2T [n=128][k=128]
__global__ __launch_bounds__(256) void knnconv_wprep(const float* __restrict__ W1,
                                                     const float* __restrict__ W2,
                                                     u16* __restrict__ w1bf,
                                                     u16* __restrict__ w2bf) {
  int b = blockIdx.x;
  if (b < 128) {
    int e = b * 256 + threadIdx.x;       // 32768 entries
    int n = e >> 7, kk = e & 127;
    float v;
    if (n < 128) v = W1[(128 + kk) * 128 + n];                              // W1d
    else { int n2 = n - 128; v = W1[kk * 128 + n2] - W1[(128 + kk) * 128 + n2]; }  // W1c-W1d
    w1bf[(n * 256 + ((kk * 2) ^ ((n & 7) << 4))) >> 1] = f2bf(v);
  } else {
    int e = (b - 128) * 256 + threadIdx.x;   // 16384 entries
    int n = e >> 7, kk = e & 127;
    w2bf[(n * 256 + ((kk * 2) ^ ((n & 7) << 4))) >> 1] = f2bf(W2[kk * 128 + n]);
  }
}

// ---------------------------------------------------------------- precompute a = f@W1d (bf16), c = f@(W1c-W1d)+b1 (f32)
__global__ __launch_bounds__(256) void knnconv_prec(const float* __restrict__ feat,
                                                    const u16* __restrict__ w1bf,
                                                    const float* __restrict__ b1,
                                                    u16* __restrict__ a_out,
                                                    float* __restrict__ c_out) {
  __shared__ char sW[65536];   // WT[n=256][k=128] bf16, pre-swizzled (linear copy)
  __shared__ char sF[16384];   // FA[m=64][k=128] bf16, XOR-swizzled
  const int tid = threadIdx.x;
  { // linear coalesced copy of pre-swizzled W1-combined
    const uint4* src = (const uint4*)w1bf;
    uint4* dst = (uint4*)sW;
    #pragma unroll
    for (int r = 0; r < 16; ++r) dst[r * 256 + tid] = src[r * 256 + tid];
  }
  { // stage FA rows (bf16x8 per lane)
    int sub = tid & 15, r0 = tid >> 4;
    int m0 = blockIdx.x * 64;
    for (int rr = 0; rr < 4; ++rr) {
      int r = r0 + rr * 16;
      const float* src = feat + (m0 + r) * 128 + sub * 8;
      float4 v0 = *(const float4*)src;
      float4 v1 = *(const float4*)(src + 4);
      u32 p0 = (u32)f2bf(v0.x) | ((u32)f2bf(v0.y) << 16);
      u32 p1 = (u32)f2bf(v0.z) | ((u32)f2bf(v0.w) << 16);
      u32 p2 = (u32)f2bf(v1.x) | ((u32)f2bf(v1.y) << 16);
      u32 p3 = (u32)f2bf(v1.z) | ((u32)f2bf(v1.w) << 16);
      *(uint4*)(sF + r * 256 + ((sub * 16) ^ ((r & 7) << 4))) = make_uint4(p0, p1, p2, p3);
    }
  }
  __syncthreads();
  const int lane = tid & 63, wv = tid >> 6;
  const int l15 = lane & 15, l4 = lane >> 4;
  f32x4 acc[4][4];
  #pragma unroll
  for (int a = 0; a < 4; ++a)
    #pragma unroll
    for (int b = 0; b < 4; ++b) acc[a][b] = (f32x4){0.f, 0.f, 0.f, 0.f};
  #pragma unroll
  for (int kk = 0; kk < 4; ++kk) {
    int kb = kk * 64 + l4 * 16;
    s16x8 af[4], bfr[4];
    #pragma unroll
    for (int mt = 0; mt < 4; ++mt) {
      int row = mt * 16 + l15;
      af[mt] = *(const s16x8*)(sF + row * 256 + (kb ^ ((row & 7) << 4)));
    }
    #pragma unroll
    for (int nt = 0; nt < 4; ++nt) {
      int n = (wv * 4 + nt) * 16 + l15;
      bfr[nt] = *(const s16x8*)(sW + n * 256 + (kb ^ ((n & 7) << 4)));
    }
    #pragma unroll
    for (int mt = 0; mt < 4; ++mt)
      #pragma unroll
      for (int nt = 0; nt < 4; ++nt)
        acc[mt][nt] = MFMA_BF16(af[mt], bfr[nt], acc[mt][nt], 0, 0, 0);
  }
  int m0 = blockIdx.x * 64;
  #pragma unroll
  for (int nt = 0; nt < 4; ++nt) {
    int n = (wv * 4 + nt) * 16 + l15;
    float bias = (n >= 128) ? b1[n - 128] : 0.0f;
    #pragma unroll
    for (int mt = 0; mt < 4; ++mt)
      #pragma unroll
      for (int r = 0; r < 4; ++r) {
        int m = m0 + mt * 16 + l4 * 4 + r;    // C/D: row=(l>>4)*4+reg, col=l&15
        float v = acc[mt][nt][r];
        if (n < 128) a_out[m * 128 + n] = f2bf(v);
        else         c_out[m * 128 + (n - 128)] = v + bias;
      }
  }
}

// ---------------------------------------------------------------- fused gather + relu + GEMM2 + max
__global__ __launch_bounds__(256) void knnconv_conv(const int* __restrict__ knn,
                                                    const u16* __restrict__ a_in,
                                                    const float* __restrict__ c_in,
                                                    const u16* __restrict__ w2bf,
                                                    const float* __restrict__ b2,
                                                    float* __restrict__ out) {
  __shared__ char lds[77824];     // [0,40960): A / H2  | [40960,73728): W2T | [73728,77824): c rows
  char* sA = lds;
  char* sW = lds + 40960;
  char* sC = lds + 73728;
  const int tid = threadIdx.x;
  const int q0 = blockIdx.x * 8;

  { // stage c rows for the 8 queries
    int row = tid >> 5, ch4 = (tid & 31) * 4;
    *(float4*)(sC + (row * 128 + ch4) * 4) = *(const float4*)(c_in + (q0 + row) * 128 + ch4);
  }
  __syncthreads();
  { // copy pre-swizzled W2 bf16 (linear copy; layout already swizzled)
    const uint4* src = (const uint4*)w2bf;
    uint4* dst = (uint4*)sW;
    #pragma unroll
    for (int r = 0; r < 8; ++r) dst[r * 256 + tid] = src[r * 256 + tid];
  }
  { // stage A: row r = (query il, neighbor ke): relu(a[idx] + c[il]) -> bf16, swizzled
    int sub = tid & 15, rr = tid >> 4;
    for (int p = 0; p < 10; ++p) {
      int r = p * 16 + rr;
      int il = r / 20;
      int ke = r - il * 20;
      int idx = knn[(q0 + il) * KNNK + ke];
      uint4 av = *(const uint4*)(a_in + idx * 128 + sub * 8);
      float4 c0 = *(const float4*)(sC + (il * 128 + sub * 8) * 4);
      float4 c1 = *(const float4*)(sC + (il * 128 + sub * 8 + 4) * 4);
      float h0 = fmaxf(bf2f((u16)(av.x & 0xFFFF)) + c0.x, 0.f);
      float h1 = fmaxf(bf2f((u16)(av.x >> 16))    + c0.y, 0.f);
      float h2 = fmaxf(bf2f((u16)(av.y & 0xFFFF)) + c0.z, 0.f);
      float h3 = fmaxf(bf2f((u16)(av.y >> 16))    + c0.w, 0.f);
      float h4 = fmaxf(bf2f((u16)(av.z & 0xFFFF)) + c1.x, 0.f);
      float h5 = fmaxf(bf2f((u16)(av.z >> 16))    + c1.y, 0.f);
      float h6 = fmaxf(bf2f((u16)(av.w & 0xFFFF)) + c1.z, 0.f);
      float h7 = fmaxf(bf2f((u16)(av.w >> 16))    + c1.w, 0.f);
      u32 p0 = (u32)f2bf(h0) | ((u32)f2bf(h1) << 16);
      u32 p1 = (u32)f2bf(h2) | ((u32)f2bf(h3) << 16);
      u32 p2 = (u32)f2bf(h4) | ((u32)f2bf(h5) << 16);
      u32 p3 = (u32)f2bf(h6) | ((u32)f2bf(h7) << 16);
      *(uint4*)(sA + r * 256 + ((sub * 16) ^ ((r & 7) << 4))) = make_uint4(p0, p1, p2, p3);
    }
  }
  __syncthreads();
  const int lane = tid & 63, wv = tid >> 6;
  const int l15 = lane & 15, l4 = lane >> 4;
  f32x4 acc[10][2];
  #pragma unroll
  for (int mt = 0; mt < 10; ++mt) { acc[mt][0] = (f32x4){0,0,0,0}; acc[mt][1] = (f32x4){0,0,0,0}; }
  #pragma unroll
  for (int kk = 0; kk < 4; ++kk) {
    int kb = kk * 64 + l4 * 16;
    s16x8 b0, b1r;
    { int n = (wv * 2 + 0) * 16 + l15; b0  = *(const s16x8*)(sW + n * 256 + (kb ^ ((n & 7) << 4))); }
    { int n = (wv * 2 + 1) * 16 + l15; b1r = *(const s16x8*)(sW + n * 256 + (kb ^ ((n & 7) << 4))); }
    #pragma unroll
    for (int mt = 0; mt < 10; ++mt) {
      int row = mt * 16 + l15;
      s16x8 a = *(const s16x8*)(sA + row * 256 + (kb ^ ((row & 7) << 4)));
      acc[mt][0] = MFMA_BF16(a, b0,  acc[mt][0], 0, 0, 0);
      acc[mt][1] = MFMA_BF16(a, b1r, acc[mt][1], 0, 0, 0);
    }
  }
  __syncthreads();              // all waves done reading A before H2 overwrite
  #pragma unroll
  for (int mt = 0; mt < 10; ++mt)
    #pragma unroll
    for (int nt = 0; nt < 2; ++nt) {
      int n = (wv * 2 + nt) * 16 + l15;
      #pragma unroll
      for (int r = 0; r < 4; ++r) {
        int row = mt * 16 + l4 * 4 + r;
        *(u16*)(sA + row * 256 + n * 2) = f2bf(acc[mt][nt][r]);  // H2, plain layout
      }
    }
  __syncthreads();
  { // max over 20 neighbors + b2
    int ch = tid & 127, g = tid >> 7;
    float bias = b2[ch];
    for (int pp = 0; pp < 4; ++pp) {
      int qq = pp * 2 + g;
      float mx = -__builtin_inff();
      #pragma unroll
      for (int e = 0; e < KNNK; ++e)
        mx = fmaxf(mx, bf2f(*(const u16*)(sA + (qq * 20 + e) * 256 + ch * 2)));
      out[(q0 + qq) * 128 + ch] = mx + bias;
    }
  }
}

// ---------------------------------------------------------------- launch
extern "C" void kernel_launch(void* const* d_in, const int* in_sizes, int n_in,
                              void* d_out, int out_size, void* d_ws, size_t ws_size,
                              hipStream_t stream) {
  const float* pos  = (const float*)d_in[0];
  const float* feat = (const float*)d_in[1];
  const float* W1   = (const float*)d_in[2];
  const float* b1   = (const float*)d_in[3];
  const float* W2   = (const float*)d_in[4];
  const float* b2   = (const float*)d_in[5];
  float* out = (float*)d_out;
  char* ws = (char*)d_ws;
  // ws layout:
  //  [0,256K)      pos4 (prep..s2)  -> w1bf 64KB + w2bf 32KB (wprep..conv; after s2)
  //  [256K,1.5M)   knn_idx (s2..conv)
  //  [1.5M,14.1M)  g1 6.3MB (s1..s2) -> a_buf 4MB + c_buf 8MB (prec..conv)
  float4* pos4  = (float4*)ws;
  u16*    w1bf  = (u16*)ws;
  u16*    w2bf  = (u16*)(ws + 65536);
  int*    knn   = (int*)(ws + 262144);
  u16*    g1    = (u16*)(ws + 1572864);
  u16*    a_buf = (u16*)(ws + 1572864);
  float*  c_buf = (float*)(ws + 5767168);
  if (ws_size < 14155776) return;   // insufficient scratch (would corrupt)

  knnconv_prep<<<64, 256, 0, stream>>>(pos, pos4);
  knnconv_s1<<<2048, 256, 0, stream>>>(pos4, g1);
  knnconv_s2<<<512, 256, 0, stream>>>(pos4, g1, knn);
  knnconv_wprep<<<192, 256, 0, stream>>>(W1, W2, w1bf, w2bf);          // overwrites pos4 (dead)
  knnconv_prec<<<256, 256, 0, stream>>>(feat, w1bf, b1, a_buf, c_buf); // overwrites g1 (dead)
  knnconv_conv<<<2048, 256, 0, stream>>>(knn, a_buf, c_buf, w2bf, b2, out);
}

// Round 6
// 328.831 us; speedup vs baseline: 2.9854x; 1.1855x over previous
//
#include <hip/hip_runtime.h>

typedef unsigned short u16;
typedef unsigned int   u32;
typedef unsigned long long u64;
typedef short s16x8 __attribute__((ext_vector_type(8)));   // 8 x bf16 bits (4 VGPRs)
typedef float f32x4 __attribute__((ext_vector_type(4)));   // MFMA accumulator

#define NPTS   16384
#define KNNK   20
#define SLOTS0 24      // s0 stack slots (trigger 16, growth <= 8 => max 23)
#define TRIG0  16
#define NCH    16      // s1x chunks per query
#define CSZ    1024    // candidates per chunk
#define CCAP   20      // survivor cap per (query, chunk)  [E~5, 6.7 sigma]

#define MFMA_BF16 __builtin_amdgcn_mfma_f32_16x16x32_bf16

__device__ __forceinline__ u16 f2bf(float x) {
  u32 u = __builtin_bit_cast(u32, x);
  u32 r = (u + 0x7FFFu + ((u >> 16) & 1u)) >> 16;   // RNE
  return (u16)r;
}
__device__ __forceinline__ float bf2f(u16 b) {
  u32 u = ((u32)b) << 16;
  return __builtin_bit_cast(float, u);
}
// shared screen metric: fully-specified fma tree (identical in s0 and s1x)
__device__ __forceinline__ float dist2(float4 qp, float4 cd) {
  float dot = fmaf(qp.x, cd.x, fmaf(qp.y, cd.y, qp.z * cd.z));
  return fmaf(-2.0f, dot, qp.w + cd.w);
}

// ---------------------------------------------------------------- prep: pos4 = (x,y,z,|p|^2)
__global__ __launch_bounds__(256) void knnconv_prep(const float* __restrict__ pos,
                                                    float4* __restrict__ pos4) {
  int i = blockIdx.x * 256 + threadIdx.x;
  float x = pos[i * 3 + 0], y = pos[i * 3 + 1], z = pos[i * 3 + 2];
  float sq = (x * x + y * y) + z * z;    // f32 screen only; f64 re-rank decides final set
  pos4[i] = make_float4(x, y, z, sq);
}

// ---------------------------------------------------------------- s0: sample threshold
// grid 256 (query-group), block 512 = 8 waves; lane = query. Each wave scans 512
// samples (every 4th candidate), keeps sorted top-20 (plain f32, lazy stack);
// 8-way merge -> exact 20th-smallest sample d2 -> tau (x1.00001 safety).
__global__ __launch_bounds__(512) void knnconv_s0(const float4* __restrict__ pos4,
                                                  float* __restrict__ tau) {
  __shared__ float lds0[SLOTS0 * 512];   // 48KB stacks; aliased as md[8][64][20]
  float* sd = lds0;
  float* md = lds0;
  const int tid  = threadIdx.x;
  const int lane = tid & 63;
  const int wv   = tid >> 6;             // 0..7
  const int qg   = blockIdx.x;
  const int q    = qg * 64 + lane;
  const float4 qp = pos4[q];
  const float INF = __builtin_inff();

  float top[KNNK];
  #pragma unroll
  for (int j = 0; j < KNNK; ++j) top[j] = INF;
  float thrF = INF;
  int cnt = 0;
  const int kbase = wv * 512;            // sample index base

#define FLUSH0()                                                      \
  { _Pragma("unroll 1")                                               \
    for (int e = 0; e < SLOTS0; e += 2) {                             \
      if (!__any(e < cnt)) break;                                     \
      float lo = (e     < cnt) ? sd[e * 512 + tid]       : INF;       \
      float hi = (e + 1 < cnt) ? sd[(e + 1) * 512 + tid] : INF;       \
      float a_ = fminf(lo, hi), b_ = fmaxf(lo, hi);                   \
      lo = a_; hi = b_;                                               \
      _Pragma("unroll")                                               \
      for (int j = 0; j < KNNK; ++j) {                                \
        float t = top[j];                                             \
        float m = fminf(lo, t);                                       \
        float x = fmaxf(lo, t);                                       \
        top[j] = m;                                                   \
        lo = fminf(x, hi);                                            \
        hi = fmaxf(x, hi);                                            \
      }                                                               \
    }                                                                 \
    thrF = top[KNNK - 1];                                             \
    cnt = 0; }

  for (int t0 = 0; t0 < 512; t0 += 8) {
    float4 g[8];
    #pragma unroll
    for (int u = 0; u < 8; ++u) g[u] = pos4[(kbase + t0 + u) * 4];  // every 4th point
    #pragma unroll
    for (int u = 0; u < 8; ++u) {
      float d2 = dist2(qp, g[u]);
      sd[cnt * 512 + tid] = d2;                        // unconditional (slot <= 22 valid)
      cnt += (d2 < thrF) ? 1 : 0;                      // branchless accept
    }
    if (__any(cnt >= TRIG0)) { FLUSH0(); }
  }
  FLUSH0();

  __syncthreads();                       // stacks dead before md alias
  #pragma unroll
  for (int j = 0; j < KNNK; ++j) md[(wv * 64 + lane) * KNNK + j] = top[j];
  __syncthreads();

  if (tid < 64) {                        // 8-way merge, take 20th smallest
    int ql = tid;
    int h0=0,h1=0,h2=0,h3=0,h4=0,h5=0,h6=0,h7=0;
    float last = INF;
    for (int r = 0; r < KNNK; ++r) {     // heads stay <= 19 while r < 20
      float c0 = md[(0*64+ql)*KNNK+h0], c1 = md[(1*64+ql)*KNNK+h1];
      float c2 = md[(2*64+ql)*KNNK+h2], c3 = md[(3*64+ql)*KNNK+h3];
      float c4 = md[(4*64+ql)*KNNK+h4], c5 = md[(5*64+ql)*KNNK+h5];
      float c6 = md[(6*64+ql)*KNNK+h6], c7 = md[(7*64+ql)*KNNK+h7];
      float bv = c0; int bw = 0;
      if (c1 < bv) { bv = c1; bw = 1; }
      if (c2 < bv) { bv = c2; bw = 2; }
      if (c3 < bv) { bv = c3; bw = 3; }
      if (c4 < bv) { bv = c4; bw = 4; }
      if (c5 < bv) { bv = c5; bw = 5; }
      if (c6 < bv) { bv = c6; bw = 6; }
      if (c7 < bv) { bv = c7; bw = 7; }
      last = bv;
      h0 += (bw==0); h1 += (bw==1); h2 += (bw==2); h3 += (bw==3);
      h4 += (bw==4); h5 += (bw==5); h6 += (bw==6); h7 += (bw==7);
    }
    tau[qg * 64 + ql] = last * 1.00001f;   // covers f32-vs-f64 rank flips + 1-ulp drift
  }
}

// ---------------------------------------------------------------- s1x: screen + compact
// grid 1024 = 256 qg x 4 parts; block 4 waves; lane = query; wave chunk = 1024 cands.
// Fixed-threshold accept (no list maintenance); survivors -> per-lane LDS list -> global.
__global__ __launch_bounds__(256) void knnconv_s1x(const float4* __restrict__ pos4,
                                                   const float* __restrict__ tau,
                                                   u16* __restrict__ g1,
                                                   u16* __restrict__ gcnt) {
  __shared__ u16 sl[CCAP * 256];         // 10KB survivor lists
  const int tid  = threadIdx.x;
  const int lane = tid & 63;
  const int wv   = tid >> 6;
  const int qg    = blockIdx.x >> 2;
  const int part  = blockIdx.x & 3;
  const int chunk = part * 4 + wv;       // 0..15
  const int cbase = chunk * CSZ;
  const int q     = qg * 64 + lane;
  const float4 qp = pos4[q];
  const float tq  = tau[q];
  const float4* cp = pos4 + cbase;

  int cnt = 0;
  for (int t0 = 0; t0 < CSZ; t0 += 8) {
    float4 g[8];
    #pragma unroll
    for (int u = 0; u < 8; ++u) g[u] = cp[t0 + u];
    #pragma unroll
    for (int u = 0; u < 8; ++u) {
      float d2 = dist2(qp, g[u]);
      int slot = min(cnt, CCAP - 1);
      sl[slot * 256 + tid] = (u16)(cbase + t0 + u);    // global idx fits u16
      cnt += (d2 <= tq) ? 1 : 0;
    }
  }
  int cc = min(cnt, CCAP);
  gcnt[q * NCH + chunk] = (u16)cc;
  u16* dst = g1 + (q * NCH + chunk) * CCAP;
  for (int j = 0; j < cc; ++j) dst[j] = sl[j * 256 + tid];
}

// ---------------------------------------------------------------- s2: gather + f64 re-rank
// block = 16 queries x 16 slots; keys[16][256] u64 in LDS; rank-count with runtime T.
__global__ __launch_bounds__(256) void knnconv_s2(const float4* __restrict__ pos4,
                                                  const u16* __restrict__ g1,
                                                  const u16* __restrict__ gcnt,
                                                  int* __restrict__ knn_out) {
  __shared__ u64 keys[16 * 256];         // 32KB
  __shared__ u16 Tq[16];
  const int tid = threadIdx.x;
  const int iq = tid >> 4, s = tid & 15;
  const int q0 = blockIdx.x * 16;
  const int q = q0 + iq;

  #pragma unroll
  for (int i = 0; i < 16; ++i) keys[i * 256 + tid] = ~0ULL;
  __syncthreads();

  int off = 0, T = 0;
  #pragma unroll
  for (int j = 0; j < NCH; ++j) {
    int cj = gcnt[q * NCH + j];
    off += (j < s) ? cj : 0;
    T += cj;
  }
  if (s == 0) Tq[iq] = (u16)min(T, 256);
  int myc = gcnt[q * NCH + s];
  float4 P = pos4[q];
  for (int i = 0; i < myc; ++i) {
    int pos = off + i;
    if (pos >= 256) break;               // deterministic clamp (never hit in practice)
    int cidx = (int)g1[(q * NCH + s) * CCAP + i];
    float4 C = pos4[cidx];
    double qx = P.x, qy = P.y, qz = P.z;
    double cx = C.x, cy = C.y, cz = C.z;
    double sqq = qx * qx + qy * qy + qz * qz;
    double sqc = cx * cx + cy * cy + cz * cz;
    double dot = qx * cx + qy * cy + qz * cz;
    double d   = (sqq + sqc) - 2.0 * dot;              // exact to ~1e-16
    float df = fmaxf((float)d, 0.0f);
    keys[iq * 256 + pos] = ((u64)__builtin_bit_cast(u32, df) << 14) | (u32)cidx;
  }
  __syncthreads();

  #pragma unroll 1
  for (int t = 0; t < 16; ++t) {         // iq2 == t uniform across block
    int j = tid & 255;
    int T2 = Tq[t];
    if (j < T2) {
      u64 kj = keys[t * 256 + j];
      const u64* row = keys + t * 256;
      int r = 0;
      for (int k = 0; k < T2; ++k) r += (row[k] < kj) ? 1 : 0;
      if (r < KNNK)
        knn_out[(q0 + t) * KNNK + r] = (int)(kj & 0x3FFFu);
    }
  }
}

// ---------------------------------------------------------------- W1/W2 -> pre-swizzled bf16 (one-shot)
__global__ __launch_bounds__(256) void knnconv_wprep(const float* __restrict__ W1,
                                                     const float* __restrict__ W2,
                                                     u16* __restrict__ w1bf,
                                                     u16* __restrict__ w2bf) {
  int b = blockIdx.x;
  if (b < 128) {
    int e = b * 256 + threadIdx.x;       // 32768 entries
    int n = e >> 7, kk = e & 127;
    float v;
    if (n < 128) v = W1[(128 + kk) * 128 + n];                              // W1d
    else { int n2 = n - 128; v = W1[kk * 128 + n2] - W1[(128 + kk) * 128 + n2]; }  // W1c-W1d
    w1bf[(n * 256 + ((kk * 2) ^ ((n & 7) << 4))) >> 1] = f2bf(v);
  } else {
    int e = (b - 128) * 256 + threadIdx.x;   // 16384 entries
    int n = e >> 7, kk = e & 127;
    w2bf[(n * 256 + ((kk * 2) ^ ((n & 7) << 4))) >> 1] = f2bf(W2[kk * 128 + n]);
  }
}

// ---------------------------------------------------------------- precompute a = f@W1d (bf16), c = f@(W1c-W1d)+b1 (f32)
__global__ __launch_bounds__(256) void knnconv_prec(const float* __restrict__ feat,
                                                    const u16* __restrict__ w1bf,
                                                    const float* __restrict__ b1,
                                                    u16* __restrict__ a_out,
                                                    float* __restrict__ c_out) {
  __shared__ char sW[65536];   // WT[n=256][k=128] bf16, pre-swizzled (linear copy)
  __shared__ char sF[16384];   // FA[m=64][k=128] bf16, XOR-swizzled
  const int tid = threadIdx.x;
  { // linear coalesced copy of pre-swizzled W1-combined
    const uint4* src = (const uint4*)w1bf;
    uint4* dst = (uint4*)sW;
    #pragma unroll
    for (int r = 0; r < 16; ++r) dst[r * 256 + tid] = src[r * 256 + tid];
  }
  { // stage FA rows (bf16x8 per lane)
    int sub = tid & 15, r0 = tid >> 4;
    int m0 = blockIdx.x * 64;
    for (int rr = 0; rr < 4; ++rr) {
      int r = r0 + rr * 16;
      const float* src = feat + (m0 + r) * 128 + sub * 8;
      float4 v0 = *(const float4*)src;
      float4 v1 = *(const float4*)(src + 4);
      u32 p0 = (u32)f2bf(v0.x) | ((u32)f2bf(v0.y) << 16);
      u32 p1 = (u32)f2bf(v0.z) | ((u32)f2bf(v0.w) << 16);
      u32 p2 = (u32)f2bf(v1.x) | ((u32)f2bf(v1.y) << 16);
      u32 p3 = (u32)f2bf(v1.z) | ((u32)f2bf(v1.w) << 16);
      *(uint4*)(sF + r * 256 + ((sub * 16) ^ ((r & 7) << 4))) = make_uint4(p0, p1, p2, p3);
    }
  }
  __syncthreads();
  const int lane = tid & 63, wv = tid >> 6;
  const int l15 = lane & 15, l4 = lane >> 4;
  f32x4 acc[4][4];
  #pragma unroll
  for (int a = 0; a < 4; ++a)
    #pragma unroll
    for (int b = 0; b < 4; ++b) acc[a][b] = (f32x4){0.f, 0.f, 0.f, 0.f};
  #pragma unroll
  for (int kk = 0; kk < 4; ++kk) {
    int kb = kk * 64 + l4 * 16;
    s16x8 af[4], bfr[4];
    #pragma unroll
    for (int mt = 0; mt < 4; ++mt) {
      int row = mt * 16 + l15;
      af[mt] = *(const s16x8*)(sF + row * 256 + (kb ^ ((row & 7) << 4)));
    }
    #pragma unroll
    for (int nt = 0; nt < 4; ++nt) {
      int n = (wv * 4 + nt) * 16 + l15;
      bfr[nt] = *(const s16x8*)(sW + n * 256 + (kb ^ ((n & 7) << 4)));
    }
    #pragma unroll
    for (int mt = 0; mt < 4; ++mt)
      #pragma unroll
      for (int nt = 0; nt < 4; ++nt)
        acc[mt][nt] = MFMA_BF16(af[mt], bfr[nt], acc[mt][nt], 0, 0, 0);
  }
  int m0 = blockIdx.x * 64;
  #pragma unroll
  for (int nt = 0; nt < 4; ++nt) {
    int n = (wv * 4 + nt) * 16 + l15;
    float bias = (n >= 128) ? b1[n - 128] : 0.0f;
    #pragma unroll
    for (int mt = 0; mt < 4; ++mt)
      #pragma unroll
      for (int r = 0; r < 4; ++r) {
        int m = m0 + mt * 16 + l4 * 4 + r;    // C/D: row=(l>>4)*4+reg, col=l&15
        float v = acc[mt][nt][r];
        if (n < 128) a_out[m * 128 + n] = f2bf(v);
        else         c_out[m * 128 + (n - 128)] = v + bias;
      }
  }
}

// ---------------------------------------------------------------- fused gather + relu + GEMM2 + max
__global__ __launch_bounds__(256) void knnconv_conv(const int* __restrict__ knn,
                                                    const u16* __restrict__ a_in,
                                                    const float* __restrict__ c_in,
                                                    const u16* __restrict__ w2bf,
                                                    const float* __restrict__ b2,
                                                    float* __restrict__ out) {
  __shared__ char lds[77824];     // [0,40960): A / H2  | [40960,73728): W2T | [73728,77824): c rows
  char* sA = lds;
  char* sW = lds + 40960;
  char* sC = lds + 73728;
  const int tid = threadIdx.x;
  const int q0 = blockIdx.x * 8;

  { // stage c rows for the 8 queries
    int row = tid >> 5, ch4 = (tid & 31) * 4;
    *(float4*)(sC + (row * 128 + ch4) * 4) = *(const float4*)(c_in + (q0 + row) * 128 + ch4);
  }
  __syncthreads();
  { // copy pre-swizzled W2 bf16 (linear copy; layout already swizzled)
    const uint4* src = (const uint4*)w2bf;
    uint4* dst = (uint4*)sW;
    #pragma unroll
    for (int r = 0; r < 8; ++r) dst[r * 256 + tid] = src[r * 256 + tid];
  }
  { // stage A: row r = (query il, neighbor ke): relu(a[idx] + c[il]) -> bf16, swizzled
    int sub = tid & 15, rr = tid >> 4;
    for (int p = 0; p < 10; ++p) {
      int r = p * 16 + rr;
      int il = r / 20;
      int ke = r - il * 20;
      int idx = knn[(q0 + il) * KNNK + ke];
      uint4 av = *(const uint4*)(a_in + idx * 128 + sub * 8);
      float4 c0 = *(const float4*)(sC + (il * 128 + sub * 8) * 4);
      float4 c1 = *(const float4*)(sC + (il * 128 + sub * 8 + 4) * 4);
      float h0 = fmaxf(bf2f((u16)(av.x & 0xFFFF)) + c0.x, 0.f);
      float h1 = fmaxf(bf2f((u16)(av.x >> 16))    + c0.y, 0.f);
      float h2 = fmaxf(bf2f((u16)(av.y & 0xFFFF)) + c0.z, 0.f);
      float h3 = fmaxf(bf2f((u16)(av.y >> 16))    + c0.w, 0.f);
      float h4 = fmaxf(bf2f((u16)(av.z & 0xFFFF)) + c1.x, 0.f);
      float h5 = fmaxf(bf2f((u16)(av.z >> 16))    + c1.y, 0.f);
      float h6 = fmaxf(bf2f((u16)(av.w & 0xFFFF)) + c1.z, 0.f);
      float h7 = fmaxf(bf2f((u16)(av.w >> 16))    + c1.w, 0.f);
      u32 p0 = (u32)f2bf(h0) | ((u32)f2bf(h1) << 16);
      u32 p1 = (u32)f2bf(h2) | ((u32)f2bf(h3) << 16);
      u32 p2 = (u32)f2bf(h4) | ((u32)f2bf(h5) << 16);
      u32 p3 = (u32)f2bf(h6) | ((u32)f2bf(h7) << 16);
      *(uint4*)(sA + r * 256 + ((sub * 16) ^ ((r & 7) << 4))) = make_uint4(p0, p1, p2, p3);
    }
  }
  __syncthreads();
  const int lane = tid & 63, wv = tid >> 6;
  const int l15 = lane & 15, l4 = lane >> 4;
  f32x4 acc[10][2];
  #pragma unroll
  for (int mt = 0; mt < 10; ++mt) { acc[mt][0] = (f32x4){0,0,0,0}; acc[mt][1] = (f32x4){0,0,0,0}; }
  #pragma unroll
  for (int kk = 0; kk < 4; ++kk) {
    int kb = kk * 64 + l4 * 16;
    s16x8 b0, b1r;
    { int n = (wv * 2 + 0) * 16 + l15; b0  = *(const s16x8*)(sW + n * 256 + (kb ^ ((n & 7) << 4))); }
    { int n = (wv * 2 + 1) * 16 + l15; b1r = *(const s16x8*)(sW + n * 256 + (kb ^ ((n & 7) << 4))); }
    #pragma unroll
    for (int mt = 0; mt < 10; ++mt) {
      int row = mt * 16 + l15;
      s16x8 a = *(const s16x8*)(sA + row * 256 + (kb ^ ((row & 7) << 4)));
      acc[mt][0] = MFMA_BF16(a, b0,  acc[mt][0], 0, 0, 0);
      acc[mt][1] = MFMA_BF16(a, b1r, acc[mt][1], 0, 0, 0);
    }
  }
  __syncthreads();              // all waves done reading A before H2 overwrite
  #pragma unroll
  for (int mt = 0; mt < 10; ++mt)
    #pragma unroll
    for (int nt = 0; nt < 2; ++nt) {
      int n = (wv * 2 + nt) * 16 + l15;
      #pragma unroll
      for (int r = 0; r < 4; ++r) {
        int row = mt * 16 + l4 * 4 + r;
        *(u16*)(sA + row * 256 + n * 2) = f2bf(acc[mt][nt][r]);  // H2, plain layout
      }
    }
  __syncthreads();
  { // max over 20 neighbors + b2
    int ch = tid & 127, g = tid >> 7;
    float bias = b2[ch];
    for (int pp = 0; pp < 4; ++pp) {
      int qq = pp * 2 + g;
      float mx = -__builtin_inff();
      #pragma unroll
      for (int e = 0; e < KNNK; ++e)
        mx = fmaxf(mx, bf2f(*(const u16*)(sA + (qq * 20 + e) * 256 + ch * 2)));
      out[(q0 + qq) * 128 + ch] = mx + bias;
    }
  }
}

// ---------------------------------------------------------------- launch
extern "C" void kernel_launch(void* const* d_in, const int* in_sizes, int n_in,
                              void* d_out, int out_size, void* d_ws, size_t ws_size,
                              hipStream_t stream) {
  const float* pos  = (const float*)d_in[0];
  const float* feat = (const float*)d_in[1];
  const float* W1   = (const float*)d_in[2];
  const float* b1   = (const float*)d_in[3];
  const float* W2   = (const float*)d_in[4];
  const float* b2   = (const float*)d_in[5];
  float* out = (float*)d_out;
  char* ws = (char*)d_ws;
  // ws layout:
  //  [0,256K)              pos4 (prep..s2)  -> w1bf 64KB + w2bf 32KB (wprep..conv)
  //  [256K,1.5M)           knn_idx (s2..conv)
  //  [1.5M,12.06M)         g1 survivors 16384x16x20 u16 (s1x..s2) -> a_buf/c_buf (prec..conv)
  //  [12.06M,12.58M)       gcnt 16384x16 u16 (s1x..s2)
  //  [12.58M,12.65M)       tau 16384 f32 (s0..s1x)
  float4* pos4  = (float4*)ws;
  u16*    w1bf  = (u16*)ws;
  u16*    w2bf  = (u16*)(ws + 65536);
  int*    knn   = (int*)(ws + 262144);
  u16*    g1    = (u16*)(ws + 1572864);
  u16*    gcnt  = (u16*)(ws + 12058624);
  float*  tau   = (float*)(ws + 12582912);
  u16*    a_buf = (u16*)(ws + 1572864);
  float*  c_buf = (float*)(ws + 5767168);
  if (ws_size < 14155776) return;   // insufficient scratch (would corrupt)

  knnconv_prep<<<64, 256, 0, stream>>>(pos, pos4);
  knnconv_s0<<<256, 512, 0, stream>>>(pos4, tau);
  knnconv_s1x<<<1024, 256, 0, stream>>>(pos4, tau, g1, gcnt);
  knnconv_s2<<<1024, 256, 0, stream>>>(pos4, g1, gcnt, knn);
  knnconv_wprep<<<192, 256, 0, stream>>>(W1, W2, w1bf, w2bf);          // overwrites pos4 (dead)
  knnconv_prec<<<256, 256, 0, stream>>>(feat, w1bf, b1, a_buf, c_buf); // overwrites g1 (dead)
  knnconv_conv<<<2048, 256, 0, stream>>>(knn, a_buf, c_buf, w2bf, b2, out);
}